// Round 1
// baseline (135.876 us; speedup 1.0000x reference)
//
#include <hip/hip_runtime.h>

// Morphological dilation: out[p,i,j] = max_{r,c}(xpad[p,i+r,j+c] + w[p,r,c]) + bias[p]
// p = b*C + c plane index (1024 planes), H=W=128, 5x5 window, pad=2, stride=1, fp32.
// Zero padding participates: OOB tap value is 0 + w[r][c].

static constexpr int H = 128, W = 128, KH = 5, KW = 5, PAD = 2;
static constexpr int RBAND = 32;            // output rows per block
static constexpr int NBANDS = H / RBAND;    // 4

#define MAX3(a, b, c) fmaxf(fmaxf((a), (b)), (c))

__global__ __launch_bounds__(128) void dilation_kernel(
    const float* __restrict__ x,
    const float* __restrict__ wgt,
    const float* __restrict__ bias,
    float* __restrict__ out)
{
    const int plane = blockIdx.x / NBANDS;   // b*C + c
    const int band  = blockIdx.x % NBANDS;
    const int j = threadIdx.x;               // output column 0..127

    const float* __restrict__ xp = x   + (size_t)plane * (H * W);
    float*       __restrict__ op = out + (size_t)plane * (H * W);
    const float* __restrict__ wp = wgt + plane * (KH * KW);

    // 25 weights + bias: address depends only on blockIdx -> wave-uniform -> SGPRs
    float wk[KH][KW];
#pragma unroll
    for (int r = 0; r < KH; ++r)
#pragma unroll
        for (int c = 0; c < KW; ++c)
            wk[r][c] = wp[r * KW + c];
    const float bi = bias[plane];

    // Per-thread clamped column offsets (address-safe) + validity for zero-padding
    int  colc[KW];
    bool colok[KW];
#pragma unroll
    for (int c = 0; c < KW; ++c) {
        int col = j + c - PAD;
        colok[c] = (col >= 0) && (col < W);
        colc[c]  = min(max(col, 0), W - 1);
    }

    const int i0 = band * RBAND;

    // Sliding window: slot t%5 holds row (i0 - PAD + t), 5 columns each.
    // Fully unrolled loop below -> all slot indices compile-time (no scratch).
    float win[KH][KW];

    // Preload t = 0..3 (rows i0-2 .. i0+1)
#pragma unroll
    for (int t = 0; t < KH - 1; ++t) {
        const int row   = i0 - PAD + t;
        const bool rowok = (row >= 0) && (row < H);
        const int rowc  = min(max(row, 0), H - 1);
        const float* rp = xp + rowc * W;
#pragma unroll
        for (int c = 0; c < KW; ++c)
            win[t][c] = (rowok && colok[c]) ? rp[colc[c]] : 0.0f;
    }

#pragma unroll
    for (int ii = 0; ii < RBAND; ++ii) {
        const int i = i0 + ii;

        // Load row i+2 into slot (ii+4)%5  (row >= 2 so only upper bound check)
        {
            const int row   = i + PAD;
            const bool rowok = (row < H);
            const int rowc  = min(row, H - 1);
            const float* rp = xp + rowc * W;
            const int slot  = (ii + KH - 1) % KH;
#pragma unroll
            for (int c = 0; c < KW; ++c)
                win[slot][c] = (rowok && colok[c]) ? rp[colc[c]] : 0.0f;
        }

        // v[r*5+c] = tap value; window row r lives in slot (ii+r)%5
        float v[KH * KW];
#pragma unroll
        for (int r = 0; r < KH; ++r) {
            const int s = (ii + r) % KH;
#pragma unroll
            for (int c = 0; c < KW; ++c)
                v[r * KW + c] = win[s][c] + wk[r][c];
        }

        // 25 -> 1 max tree, 12 x v_max3_f32, depth 3
        const float u0 = MAX3(v[0],  v[1],  v[2]);
        const float u1 = MAX3(v[3],  v[4],  v[5]);
        const float u2 = MAX3(v[6],  v[7],  v[8]);
        const float u3 = MAX3(v[9],  v[10], v[11]);
        const float u4 = MAX3(v[12], v[13], v[14]);
        const float u5 = MAX3(v[15], v[16], v[17]);
        const float u6 = MAX3(v[18], v[19], v[20]);
        const float u7 = MAX3(v[21], v[22], v[23]);
        const float w0 = MAX3(u0, u1, u2);
        const float w1 = MAX3(u3, u4, u5);
        const float w2 = MAX3(u6, u7, v[24]);
        const float m  = MAX3(w0, w1, w2);

        op[i * W + j] = m + bi;
    }
}

extern "C" void kernel_launch(void* const* d_in, const int* in_sizes, int n_in,
                              void* d_out, int out_size, void* d_ws, size_t ws_size,
                              hipStream_t stream) {
    const float* x    = (const float*)d_in[0];
    const float* wgt  = (const float*)d_in[1];
    const float* bias = (const float*)d_in[2];
    float* out        = (float*)d_out;

    const int planes = in_sizes[2];          // B*C = 1024
    dim3 grid(planes * NBANDS);              // 4096 blocks
    dim3 block(W);                           // 128 threads = 2 waves
    dilation_kernel<<<grid, block, 0, stream>>>(x, wgt, bias, out);
}

// Round 2
// 126.736 us; speedup vs baseline: 1.0721x; 1.0721x over previous
//
#include <hip/hip_runtime.h>

// Morphological dilation: out[p,i,j] = max_{r,c}(xpad[p,i+r,j+c] + w[p,r,c]) + bias[p]
// p = plane (B*C = 1024), H=W=128, 5x5 window, pad=2, stride=1, fp32.
// Zero padding participates: OOB tap value is 0 + w[r][c].
// R2: 4 outputs/thread (float4), sliding 5-row register window, 3 vector loads
// per row advance (float2 | float4 | float2 covering the 8 needed columns),
// bias pre-folded into weights.

static constexpr int H = 128, W = 128, KH = 5, KW = 5, PAD = 2;
static constexpr int RSTRIP = 8;          // output rows per thread
static constexpr int RBAND  = 64;         // output rows per block (8 row-streams)
static constexpr int BANDS  = H / RBAND;  // 2 blocks per plane

#define MAX3(a, b, c) fmaxf(fmaxf((a), (b)), (c))

__global__ __launch_bounds__(256) void dilation_kernel(
    const float* __restrict__ x,
    const float* __restrict__ wgt,
    const float* __restrict__ bias,
    float* __restrict__ out)
{
    const int plane = blockIdx.x / BANDS;
    const int band  = blockIdx.x % BANDS;
    const int tid = threadIdx.x;
    const int cg  = tid & 31;     // column group: 4 cols each, 32 groups = 128 cols
    const int rs  = tid >> 5;     // row stream 0..7
    const int j0  = cg * 4;
    const int base = band * RBAND + rs * RSTRIP;

    const float* __restrict__ xp = x   + (size_t)plane * (H * W);
    float*       __restrict__ op = out + (size_t)plane * (H * W);
    const float* __restrict__ wp = wgt + plane * (KH * KW);

    // Plane-uniform: weights (+bias folded) scalarize to SGPRs.
    const float bi = bias[plane];
    float wk[KH * KW];
#pragma unroll
    for (int i = 0; i < KH * KW; ++i) wk[i] = wp[i] + bi;

    // Column-edge handling: window needs cols j0-2 .. j0+5 (8 floats).
    // L = float2 @ j0-2 (invalid for cg==0), M = float4 @ j0 (always valid),
    // R = float2 @ j0+4 (invalid for cg==31). Clamped addresses stay in-plane.
    const bool cgL = (cg > 0);
    const bool cgR = (cg < 31);
    const int colL = cgL ? (j0 - 2) : 0;
    const int colR = cgR ? (j0 + 4) : (W - 2);

    // Sliding window: win[slot][0..7] = 8 columns of one input row.
    // Slot of input row (i-2+r) at iteration it is (it+r)%5; fully unrolled
    // below so all indices are compile-time (registers, no scratch).
    float win[KH][8];

#define LOAD_ROW(SLOT, ROW, ROK)                                              \
    do {                                                                      \
        const bool rok_ = (ROK);                                              \
        const int  rowc_ = rok_ ? (ROW) : 0;                                  \
        const float* rp_ = xp + rowc_ * W;                                    \
        const float2 L_ = *reinterpret_cast<const float2*>(rp_ + colL);       \
        const float4 M_ = *reinterpret_cast<const float4*>(rp_ + j0);         \
        const float2 R_ = *reinterpret_cast<const float2*>(rp_ + colR);       \
        win[SLOT][0] = (rok_ && cgL) ? L_.x : 0.0f;                           \
        win[SLOT][1] = (rok_ && cgL) ? L_.y : 0.0f;                           \
        win[SLOT][2] = rok_ ? M_.x : 0.0f;                                    \
        win[SLOT][3] = rok_ ? M_.y : 0.0f;                                    \
        win[SLOT][4] = rok_ ? M_.z : 0.0f;                                    \
        win[SLOT][5] = rok_ ? M_.w : 0.0f;                                    \
        win[SLOT][6] = (rok_ && cgR) ? R_.x : 0.0f;                           \
        win[SLOT][7] = (rok_ && cgR) ? R_.y : 0.0f;                           \
    } while (0)

    // Preload rows base-2 .. base+1 into slots 0..3 (only lower bound can trip).
#pragma unroll
    for (int t = 0; t < KH - 1; ++t) {
        const int row = base - PAD + t;
        LOAD_ROW(t, row, row >= 0);
    }

#pragma unroll
    for (int it = 0; it < RSTRIP; ++it) {
        const int i = base + it;

        // Load row i+2 into slot (it+4)%5 (row >= 2, only upper bound can trip).
        {
            const int row = i + PAD;
            const int slot = (it + KH - 1) % KH;
            LOAD_ROW(slot, row < H ? row : (H - 1), row < H);
        }

        float res[4];
#pragma unroll
        for (int k = 0; k < 4; ++k) {
            float v[KH * KW];
#pragma unroll
            for (int r = 0; r < KH; ++r) {
                const int s = (it + r) % KH;
#pragma unroll
                for (int c = 0; c < KW; ++c)
                    v[r * KW + c] = win[s][k + c] + wk[r * KW + c];
            }
            const float u0 = MAX3(v[0],  v[1],  v[2]);
            const float u1 = MAX3(v[3],  v[4],  v[5]);
            const float u2 = MAX3(v[6],  v[7],  v[8]);
            const float u3 = MAX3(v[9],  v[10], v[11]);
            const float u4 = MAX3(v[12], v[13], v[14]);
            const float u5 = MAX3(v[15], v[16], v[17]);
            const float u6 = MAX3(v[18], v[19], v[20]);
            const float u7 = MAX3(v[21], v[22], v[23]);
            const float w0 = MAX3(u0, u1, u2);
            const float w1 = MAX3(u3, u4, u5);
            const float w2 = MAX3(u6, u7, v[24]);
            res[k] = MAX3(w0, w1, w2);
        }

        float4 o;
        o.x = res[0]; o.y = res[1]; o.z = res[2]; o.w = res[3];
        *reinterpret_cast<float4*>(op + i * W + j0) = o;
    }
#undef LOAD_ROW
}

extern "C" void kernel_launch(void* const* d_in, const int* in_sizes, int n_in,
                              void* d_out, int out_size, void* d_ws, size_t ws_size,
                              hipStream_t stream) {
    const float* x    = (const float*)d_in[0];
    const float* wgt  = (const float*)d_in[1];
    const float* bias = (const float*)d_in[2];
    float* out        = (float*)d_out;

    const int planes = in_sizes[2];          // B*C = 1024
    dim3 grid(planes * BANDS);               // 2048 blocks
    dim3 block(256);                         // 4 waves
    dilation_kernel<<<grid, block, 0, stream>>>(x, wgt, bias, out);
}

// Round 3
// 122.464 us; speedup vs baseline: 1.1095x; 1.0349x over previous
//
#include <hip/hip_runtime.h>

// Morphological dilation: out[p,i,j] = max_{r,c}(xpad[p,i+r,j+c] + w[p,r,c]) + bias[p]
// p = plane (B*C=1024), H=W=128, 5x5, pad=2, stride=1, fp32. Zero pad participates.
// R3: quarter-plane blocks; zero-padded 36x132 LDS tile staged via async
// global_load_lds; compute loop = 2 ds_read_b128 per row-advance, no bounds logic.

static constexpr int H = 128, W = 128, KH = 5, KW = 5, PAD = 2;
static constexpr int QROWS = 32;             // output rows per block
static constexpr int PROWS = QROWS + KH - 1; // 36 padded rows in LDS
static constexpr int PCOLS = W + 2 * PAD;    // 132 padded cols
static constexpr int NQ    = H / QROWS;      // 4 blocks per plane

#define MAX3(a, b, c) fmaxf(fmaxf((a), (b)), (c))

__device__ inline void gload_lds4(const float* g, float* l) {
    __builtin_amdgcn_global_load_lds(
        (const __attribute__((address_space(1))) void*)g,
        (__attribute__((address_space(3))) void*)l, 4, 0, 0);
}

__global__ __launch_bounds__(256) void dilation_kernel(
    const float* __restrict__ x,
    const float* __restrict__ wgt,
    const float* __restrict__ bias,
    float* __restrict__ out)
{
    __shared__ float tile[PROWS * PCOLS];    // 36 x 132 floats = 19008 B

    const int plane = blockIdx.x / NQ;
    const int q     = blockIdx.x % NQ;
    const int tid   = threadIdx.x;

    const float* __restrict__ xp = x   + (size_t)plane * (H * W);
    float*       __restrict__ op = out + (size_t)plane * (H * W);
    const float* __restrict__ wp = wgt + plane * (KH * KW);

    // ---- zero the LDS padding (disjoint from staged interior) ----
    // Column edges (cols 0,1,130,131) of all 36 rows:
    if (tid < 2 * PROWS) {
        const int r   = tid >> 1;
        const int off = (tid & 1) ? (PCOLS - 2) : 0;
        tile[r * PCOLS + off]     = 0.0f;
        tile[r * PCOLS + off + 1] = 0.0f;
    }
    // Out-of-image halo rows (block-uniform branches):
    if (q == 0 && tid < PCOLS) {             // tile rows 0,1 = input rows -2,-1
        tile[tid]         = 0.0f;
        tile[PCOLS + tid] = 0.0f;
    }
    if (q == NQ - 1 && tid < PCOLS) {        // tile rows 34,35 = input rows 128,129
        tile[(PROWS - 2) * PCOLS + tid] = 0.0f;
        tile[(PROWS - 1) * PCOLS + tid] = 0.0f;
    }

    // ---- async stage: 36 rows x 512B, one row = 2 wave-ops of 64x4B ----
    const int wave = tid >> 6;
    const int lane = tid & 63;
    const int row0 = q * QROWS - PAD;        // input row of tile row 0
#pragma unroll
    for (int chunk = 0; chunk < 2 * PROWS; chunk += 4) {
        const int ch   = chunk + wave;       // wave-uniform
        const int pr   = ch >> 1;
        const int half = (ch & 1) * 64;
        const int irow = row0 + pr;
        if (irow >= 0 && irow < H) {         // wave-uniform branch
            gload_lds4(xp + irow * W + half + lane,
                       &tile[pr * PCOLS + PAD + half]);
        }
    }

    __syncthreads();                         // drains vmcnt + lgkmcnt

    // ---- weights stay SGPR (uniform loads); bias added at the end ----
    float wk[KH * KW];
#pragma unroll
    for (int i = 0; i < KH * KW; ++i) wk[i] = wp[i];
    const float bi = bias[plane];

    const int cg = tid & 31;                 // 32 column groups x 4 cols
    const int rs = tid >> 5;                 // 8 row streams x 4 rows
    const int j0 = cg * 4;
    const int tb = rs * 4;                   // local output row base

    // Sliding 5-row register window of 8 padded cols (j0..j0+7).
    float win[KH][8];

#define LOAD_TROW(SLOT, PR)                                                   \
    do {                                                                      \
        const float* rp_ = &tile[(PR) * PCOLS + j0];                          \
        const float4 a_ = *reinterpret_cast<const float4*>(rp_);              \
        const float4 b_ = *reinterpret_cast<const float4*>(rp_ + 4);          \
        win[SLOT][0] = a_.x; win[SLOT][1] = a_.y;                             \
        win[SLOT][2] = a_.z; win[SLOT][3] = a_.w;                             \
        win[SLOT][4] = b_.x; win[SLOT][5] = b_.y;                             \
        win[SLOT][6] = b_.z; win[SLOT][7] = b_.w;                             \
    } while (0)

#pragma unroll
    for (int t = 0; t < KH - 1; ++t)
        LOAD_TROW(t, tb + t);

#pragma unroll
    for (int it = 0; it < 4; ++it) {
        LOAD_TROW((it + KH - 1) % KH, tb + it + KH - 1);

        float res[4];
#pragma unroll
        for (int k = 0; k < 4; ++k) {
            float v[KH * KW];
#pragma unroll
            for (int r = 0; r < KH; ++r) {
                const int s = (it + r) % KH;
#pragma unroll
                for (int c = 0; c < KW; ++c)
                    v[r * KW + c] = win[s][k + c] + wk[r * KW + c];
            }
            const float u0 = MAX3(v[0],  v[1],  v[2]);
            const float u1 = MAX3(v[3],  v[4],  v[5]);
            const float u2 = MAX3(v[6],  v[7],  v[8]);
            const float u3 = MAX3(v[9],  v[10], v[11]);
            const float u4 = MAX3(v[12], v[13], v[14]);
            const float u5 = MAX3(v[15], v[16], v[17]);
            const float u6 = MAX3(v[18], v[19], v[20]);
            const float u7 = MAX3(v[21], v[22], v[23]);
            const float w0 = MAX3(u0, u1, u2);
            const float w1 = MAX3(u3, u4, u5);
            const float w2 = MAX3(u6, u7, v[24]);
            res[k] = MAX3(w0, w1, w2) + bi;
        }

        float4 o;
        o.x = res[0]; o.y = res[1]; o.z = res[2]; o.w = res[3];
        const int grow = q * QROWS + tb + it;
        *reinterpret_cast<float4*>(op + grow * W + j0) = o;
    }
#undef LOAD_TROW
}

extern "C" void kernel_launch(void* const* d_in, const int* in_sizes, int n_in,
                              void* d_out, int out_size, void* d_ws, size_t ws_size,
                              hipStream_t stream) {
    const float* x    = (const float*)d_in[0];
    const float* wgt  = (const float*)d_in[1];
    const float* bias = (const float*)d_in[2];
    float* out        = (float*)d_out;

    const int planes = in_sizes[2];          // B*C = 1024
    dim3 grid(planes * NQ);                  // 4096 blocks
    dim3 block(256);                         // 4 waves
    dilation_kernel<<<grid, block, 0, stream>>>(x, wgt, bias, out);
}